// Round 19
// baseline (274.632 us; speedup 1.0000x reference)
//
#include <hip/hip_runtime.h>
#include <hip/hip_bf16.h>

// Flash-attention fwd, fp32 in/out, bf16 MFMA compute.
// B=64, L=1024, D=64. scale=1/sqrt(512). mask(int32)!=0 -> -1e9.
// R19: ZERO-BARRIER wave-independent design. Waves own disjoint q-rows and
//      now own their entire pipeline:
//  - K fragments loaded DIRECTLY global->register in MFMA A-layout (no k_lds;
//    L2-hot via XCD swizzle; 128B lines fully consumed)
//  - V staged into a WAVE-PRIVATE LDS quarter (same-wave write->read is
//    in-order on the DS pipe; no sync needed)
//  - P relayout via wave-private p_lds (as R8/R16/R18)
//  - NO __syncthreads anywhere: no convoy, no counter drains, 12 free-running
//    wave-chains per CU hide each other's latency
//  - kept from R16/R18 (proven/neutral): XCD decode, 2-deep mask ring,
//    mask-as-MFMA-C-seed, invT pre-folded into Q

typedef __attribute__((ext_vector_type(4))) float f32x4;
typedef __attribute__((ext_vector_type(8))) short bf16x8;
typedef __attribute__((ext_vector_type(4))) short short4v;

constexpr int B_ = 64;
constexpr int L_ = 1024;
constexpr int D_ = 64;
constexpr int QBLK = 64;     // q rows per block (4 waves x 16)
constexpr int KV = 64;       // keys per tile
constexpr int NKV = L_ / KV; // 16 tiles
constexpr int STR = 72;      // shorts per LDS row (64 + 8 pad)
constexpr float INV_TEMP = 0.04419417382415922f; // 1/sqrt(512)
constexpr float NEG = -1e9f;

__device__ inline short f2bf(float f) {
  __hip_bfloat16 h = __float2bfloat16(f);
  short s; __builtin_memcpy(&s, &h, 2);
  return s;
}

__global__ __launch_bounds__(256, 3) void attn_fwd(
    const float* __restrict__ Q, const float* __restrict__ K,
    const float* __restrict__ V, const int* __restrict__ M,
    float* __restrict__ O)
{
  __shared__ short vt_lds[4][D_][STR];  // 36.9 KB, one quarter per wave
  __shared__ short p_lds[4][16][STR];   //  9.2 KB  -> 46.1 KB, 3 blocks/CU

  const int tid  = threadIdx.x;
  const int w    = tid >> 6;
  const int lane = tid & 63;
  const int g    = lane >> 4;
  const int c    = lane & 15;

  // ---- XCD-aware decode: all 16 q-tile blocks of batch b on one XCD
  const int p   = blockIdx.x;
  const int xcd = p & 7;
  const int j   = p >> 3;           // 0..127
  const int b   = xcd + 8 * (j >> 4);
  const int q0  = (j & 15) * QBLK;

  short (*vt)[STR] = vt_lds[w];     // this wave's private V^T quarter
  short (*pl)[STR] = p_lds[w];      // this wave's private P buffer

  // ---- Q fragment (B operand of swapped QK^T), invT pre-folded
  bf16x8 qf[2];
  {
    const float* qp = Q + ((size_t)b * L_ + q0 + w * 16 + c) * D_ + g * 8;
#pragma unroll
    for (int ks = 0; ks < 2; ++ks) {
      f32x4 x0 = *(const f32x4*)(qp + ks * 32);
      f32x4 x1 = *(const f32x4*)(qp + ks * 32 + 4);
      bf16x8 t;
      t[0] = f2bf(x0[0] * INV_TEMP); t[1] = f2bf(x0[1] * INV_TEMP);
      t[2] = f2bf(x0[2] * INV_TEMP); t[3] = f2bf(x0[3] * INV_TEMP);
      t[4] = f2bf(x1[0] * INV_TEMP); t[5] = f2bf(x1[1] * INV_TEMP);
      t[6] = f2bf(x1[2] * INV_TEMP); t[7] = f2bf(x1[3] * INV_TEMP);
      qf[ks] = t;
    }
  }

  const float* Kb = K + (size_t)b * L_ * D_;
  const float* Vb = V + (size_t)b * L_ * D_;
  // mask, swapped layout: lane's own row q=w*16+c, keys f*16+4g+0..3 per tile
  const int* mlane = M + (size_t)b * L_ * L_ + (size_t)(q0 + w * 16 + c) * L_ + 4 * g;

  int4 mA[4], mB[4];                 // mask ring, 2 tiles deep
  auto load_m = [&](int t, int4 (&mr)[4]) {
#pragma unroll
    for (int f = 0; f < 4; ++f) mr[f] = *(const int4*)(mlane + t * KV + f * 16);
  };

  f32x4 acc[4];
#pragma unroll
  for (int i = 0; i < 4; ++i) acc[i] = (f32x4){0.f, 0.f, 0.f, 0.f};
  float m_run = -INFINITY;  // per-lane, q-row = w*16+c
  float l_run = 0.f;

  load_m(0, mA);
  load_m(1, mB);

  auto body = [&](int t, int4 (&mbuf)[4], bool refill) {
    int4 mc[4];
#pragma unroll
    for (int f = 0; f < 4; ++f) mc[f] = mbuf[f];   // consume (reg moves)
    if (refill) load_m(t + 2, mbuf);               // refill: 2-deep ring

    // ---- V tile loads (wave-private; consumed after QK^T).
    //      lane covers keys g*4+16*ii+i, d = c*4..c*4+3 (contig 16B; per
    //      instr 4 rows x 256B fully coalesced)
    f32x4 vreg[4][4];
#pragma unroll
    for (int ii = 0; ii < 4; ++ii)
#pragma unroll
      for (int i = 0; i < 4; ++i)
        vreg[ii][i] = *(const f32x4*)(Vb + (size_t)(t * KV + g * 4 + 16 * ii + i) * D_ + c * 4);

    // ---- K fragments DIRECT from global in A-layout:
    //      row = key = f*16+c, k-elem = ks*32+g*8+j (L2-hot, lines fully used)
    bf16x8 kf[4][2];
#pragma unroll
    for (int f = 0; f < 4; ++f)
#pragma unroll
      for (int ks = 0; ks < 2; ++ks) {
        const float* kp = Kb + (size_t)(t * KV + f * 16 + c) * D_ + ks * 32 + g * 8;
        f32x4 x0 = *(const f32x4*)kp;
        f32x4 x1 = *(const f32x4*)(kp + 4);
        bf16x8 kk;
        kk[0] = f2bf(x0[0]); kk[1] = f2bf(x0[1]); kk[2] = f2bf(x0[2]); kk[3] = f2bf(x0[3]);
        kk[4] = f2bf(x1[0]); kk[5] = f2bf(x1[1]); kk[6] = f2bf(x1[2]); kk[7] = f2bf(x1[3]);
        kf[f][ks] = kk;
      }

    // ---- S^T = K (Q*invT)^T + mask-bias seed : C row = key, col = q = c
    f32x4 sc[4];
#pragma unroll
    for (int f = 0; f < 4; ++f) {
      f32x4 a;
      a[0] = mc[f].x ? NEG : 0.0f;
      a[1] = mc[f].y ? NEG : 0.0f;
      a[2] = mc[f].z ? NEG : 0.0f;
      a[3] = mc[f].w ? NEG : 0.0f;
      a = __builtin_amdgcn_mfma_f32_16x16x32_bf16(kf[f][0], qf[0], a, 0, 0, 0);
      a = __builtin_amdgcn_mfma_f32_16x16x32_bf16(kf[f][1], qf[1], a, 0, 0, 0);
      sc[f] = a;
    }

    // ---- V cvt + write to own quarter: V^T[d=c*4+jj][keys g*4+16*ii..+3]
    //      (same-wave write->read: DS pipe in-order, no barrier needed)
#pragma unroll
    for (int ii = 0; ii < 4; ++ii)
#pragma unroll
      for (int jj = 0; jj < 4; ++jj) {
        short4v vt4 = { f2bf(vreg[ii][0][jj]), f2bf(vreg[ii][1][jj]),
                        f2bf(vreg[ii][2][jj]), f2bf(vreg[ii][3][jj]) };
        *(short4v*)&vt[c * 4 + jj][g * 4 + 16 * ii] = vt4;
      }

    // ---- online softmax, per-lane row (16 in-lane keys x 4 lane-groups)
    float x = sc[0][0];
#pragma unroll
    for (int f = 0; f < 4; ++f)
#pragma unroll
      for (int r = 0; r < 4; ++r) x = fmaxf(x, sc[f][r]);
    x = fmaxf(x, __shfl_xor(x, 16, 64));
    x = fmaxf(x, __shfl_xor(x, 32, 64));
    const float m_new = fmaxf(m_run, x);
    const float alpha = __expf(m_run - m_new);
    float s = 0.f;
#pragma unroll
    for (int f = 0; f < 4; ++f)
#pragma unroll
      for (int r = 0; r < 4; ++r) {
        sc[f][r] = __expf(sc[f][r] - m_new);
        s += sc[f][r];
      }
    s += __shfl_xor(s, 16, 64);
    s += __shfl_xor(s, 32, 64);
    l_run = l_run * alpha + s;
    m_run = m_new;

    // ---- rescale acc: acc rows are q=g*4+r -> alpha from lane c'=g*4+r
    float ar[4];
#pragma unroll
    for (int r = 0; r < 4; ++r)
      ar[r] = __shfl(alpha, (lane & 48) | (g * 4 + r), 64);
#pragma unroll
    for (int fd = 0; fd < 4; ++fd)
#pragma unroll
      for (int r = 0; r < 4; ++r) acc[fd][r] *= ar[r];

    // ---- P -> wave-private LDS: lane owns P[q=c][keys f*16+4g+0..3]
#pragma unroll
    for (int f = 0; f < 4; ++f) {
      short4v pk = { f2bf(sc[f][0]), f2bf(sc[f][1]),
                     f2bf(sc[f][2]), f2bf(sc[f][3]) };
      *(short4v*)&pl[c][f * 16 + 4 * g] = pk;
    }

    // ---- O += P V (reads own quarter; in-order after the writes above)
#pragma unroll
    for (int ks = 0; ks < 2; ++ks) {
      bf16x8 pa = *(const bf16x8*)&pl[c][ks * 32 + g * 8];
#pragma unroll
      for (int fd = 0; fd < 4; ++fd) {
        bf16x8 vb = *(const bf16x8*)&vt[fd * 16 + c][ks * 32 + g * 8];
        acc[fd] = __builtin_amdgcn_mfma_f32_16x16x32_bf16(pa, vb, acc[fd], 0, 0, 0);
      }
    }
    // NO barrier: next tile's LDS writes are ordered after this tile's
    // reads by the per-wave in-order DS pipe.
  };

  for (int tt = 0; tt < NKV; tt += 2) {
    body(tt,     mA, tt + 2 < NKV);   // consume m(tt),   refill -> m(tt+2)
    body(tt + 1, mB, tt + 3 < NKV);   // consume m(tt+1), refill -> m(tt+3)
  }

  // ---- epilogue: acc[fd][r] = O[q=g*4+r][d=fd*16+c]; l lives at lane c'=q
  const float li = 1.0f / l_run;
  float lr[4];
#pragma unroll
  for (int r = 0; r < 4; ++r)
    lr[r] = __shfl(li, (lane & 48) | (g * 4 + r), 64);
  float* orow = O + ((size_t)b * L_ + q0 + w * 16 + g * 4) * D_;
#pragma unroll
  for (int fd = 0; fd < 4; ++fd)
#pragma unroll
    for (int r = 0; r < 4; ++r)
      orow[(size_t)r * D_ + fd * 16 + c] = acc[fd][r] * lr[r];
}

extern "C" void kernel_launch(void* const* d_in, const int* in_sizes, int n_in,
                              void* d_out, int out_size, void* d_ws, size_t ws_size,
                              hipStream_t stream) {
  const float* q = (const float*)d_in[0];
  const float* k = (const float*)d_in[1];
  const float* v = (const float*)d_in[2];
  const int* m = (const int*)d_in[3]; // jax bool shipped as int32
  float* o = (float*)d_out;
  attn_fwd<<<dim3(1024), 256, 0, stream>>>(q, k, v, m, o);
}